// Round 8
// baseline (18494.551 us; speedup 1.0000x reference)
//
#include <hip/hip_runtime.h>
#include <hip/hip_bf16.h>
#include <math.h>

// Problem dims
#define T_N   4096
#define IN_N  1024
#define H_N   2048
#define OUT_N 1024

// Recurrence decomposition (v5 core): KD blocks per direction, RPB rows each.
#define KD   64
#define RPB  32        // H_N / KD
#define RTH  1024      // 16 waves, 2 rows per wave
#define NREC 128       // 2 * KD recurrence blocks
#define NGEMM 1024     // xw-GEMM blocks: 2 dir x 64 t-chunks x 8 quads

// Workspace byte offsets (total 128 MiB + 1 KiB)
#define XW_F_OFF 0ull
#define XW_B_OFF 33554432ull
#define HF_OFF   67108864ull
#define HB_OFF   100663296ull
#define PROG_OFF 134217728ull
// progf[64]@+0B, progb[64]@+256B, cntf[64]@+512B, cntb[64]@+768B

__global__ __launch_bounds__(256) void init_prog_kernel(unsigned* __restrict__ p) {
  p[threadIdx.x] = 0u;   // zero 256 words: flags + chunk counters, both dirs
}

// ---------------------------------------------------------------------------
// Mega-kernel: two block roles, co-resident.
//  blockIdx < NREC: persistent recurrence (EXACT v5 fenceless core) on 128 CUs
//  else: xw-GEMM tile groups on the other 128 CUs, t-chunk-ordered, publishing
//        per-chunk readiness counters the recurrence gates on.
// All cross-block data goes through sc1 (agent-scope relaxed atomics, LLC
// coherence point). Zero HW fences. Deadlock-free: GEMM blocks never wait;
// rec blocks occupy at most 1 CU each, so queued rec blocks always schedule.
// ---------------------------------------------------------------------------
__global__ __launch_bounds__(RTH, 4) void mega_kernel(
    const float* __restrict__ x,
    const float* __restrict__ Wxf, const float* __restrict__ bhf,
    const float* __restrict__ Wxb, const float* __restrict__ bhb,
    const float* __restrict__ Whf, const float* __restrict__ Whb,
    float* __restrict__ xwf, float* __restrict__ xwb,
    float* __restrict__ hf, float* __restrict__ hb,
    unsigned* __restrict__ prog)
{
  __shared__ __align__(16) float hs[H_N];       // rec role: 8 KB
  __shared__ float As[4][16][65];               // gemm role: 33.3 KB
  __shared__ float Bs[4][16][65];

  const int b = blockIdx.x;
  if (b < NREC) {
    // ================= recurrence role (v5 core + chunk gate) =============
    const bool fwd = (b < KD);
    const int bb   = fwd ? b : b - KD;
    const int rb   = bb * RPB;
    const float* __restrict__ Wh = fwd ? Whf : Whb;
    const float* __restrict__ xw = fwd ? xwf : xwb;
    float* __restrict__ hist     = fwd ? hf : hb;
    unsigned* __restrict__ flg   = prog + (fwd ? 0 : 64);
    unsigned* __restrict__ cnt   = prog + (fwd ? 128 : 192);

    const int w     = threadIdx.x >> 6;   // wave 0..15
    const int lane  = threadIdx.x & 63;
    const int jbase = lane << 2;          // 0..252
    const int r0    = rb + 2 * w;         // this wave's two rows

    // One-time: weight slice into registers (64 VGPRs/lane), pinned.
    float4 wv[2][8];
#pragma unroll
    for (int q = 0; q < 2; ++q)
#pragma unroll
      for (int k = 0; k < 8; ++k)
        wv[q][k] = *(const float4*)(Wh + (size_t)(r0 + q) * H_N + k * 256 + jbase);
#pragma unroll
    for (int q = 0; q < 2; ++q)
#pragma unroll
      for (int k = 0; k < 8; ++k)
        asm volatile("" : "+v"(wv[q][k].x), "+v"(wv[q][k].y),
                          "+v"(wv[q][k].z), "+v"(wv[q][k].w));

    for (int s = 0; s < T_N; ++s) {
      const int t  = fwd ? s : (T_N - 1 - s);
      const int pt = fwd ? (t - 1) : (t + 1);
      const int chunk = t >> 6;

      // wave0 polls: producer flags (s>0) AND xw chunk readiness (==32 tiles)
      if (w == 0) {
        for (;;) {
          unsigned p = (s > 0)
              ? __hip_atomic_load(flg + lane, __ATOMIC_RELAXED,
                                  __HIP_MEMORY_SCOPE_AGENT)
              : (unsigned)s;
          unsigned c = __hip_atomic_load(cnt + chunk, __ATOMIC_RELAXED,
                                         __HIP_MEMORY_SCOPE_AGENT);
          if (__all(p >= (unsigned)s && c >= 32u)) break;
          __builtin_amdgcn_s_sleep(1);
        }
        asm volatile("" ::: "memory");   // compiler barrier only
      }
      __syncthreads();   // barA: poll satisfied

      // Cooperative stage from LLC: 1024 threads x one 8B relaxed atomic.
      if (s > 0) {
        unsigned long long hv2 = __hip_atomic_load(
            (const unsigned long long*)(hist + (size_t)pt * H_N) + threadIdx.x,
            __ATOMIC_RELAXED, __HIP_MEMORY_SCOPE_AGENT);
        *((unsigned long long*)hs + threadIdx.x) = hv2;
      } else {
        *((unsigned long long*)hs + threadIdx.x) = 0ull;
      }
      // xw for our two rows: sc1 load AFTER chunk gate; consumed only at tanh.
      float xwv0 = 0.f, xwv1 = 0.f;
      if (lane == 0) {
        unsigned long long xq = __hip_atomic_load(
            (const unsigned long long*)(xw + (size_t)t * H_N + r0),
            __ATOMIC_RELAXED, __HIP_MEMORY_SCOPE_AGENT);
        xwv0 = __uint_as_float((unsigned)xq);
        xwv1 = __uint_as_float((unsigned)(xq >> 32));
      }
      __syncthreads();   // barB: staged h visible

      float acc0 = 0.f, acc1 = 0.f;
#pragma unroll
      for (int k = 0; k < 8; ++k) {
        float4 h4 = *(const float4*)(hs + k * 256 + jbase);
        acc0 = fmaf(wv[0][k].x, h4.x, acc0);
        acc0 = fmaf(wv[0][k].y, h4.y, acc0);
        acc0 = fmaf(wv[0][k].z, h4.z, acc0);
        acc0 = fmaf(wv[0][k].w, h4.w, acc0);
        acc1 = fmaf(wv[1][k].x, h4.x, acc1);
        acc1 = fmaf(wv[1][k].y, h4.y, acc1);
        acc1 = fmaf(wv[1][k].z, h4.z, acc1);
        acc1 = fmaf(wv[1][k].w, h4.w, acc1);
      }
#pragma unroll
      for (int off = 32; off > 0; off >>= 1) {
        acc0 += __shfl_xor(acc0, off, 64);
        acc1 += __shfl_xor(acc1, off, 64);
      }

      if (lane == 0) {
        union { float f; unsigned u; } h0, h1;
        h0.f = tanhf(acc0 + xwv0);
        h1.f = tanhf(acc1 + xwv1);
        unsigned* hu = (unsigned*)(hist + (size_t)t * H_N + r0);
        __hip_atomic_store(hu + 0, h0.u, __ATOMIC_RELAXED, __HIP_MEMORY_SCOPE_AGENT);
        __hip_atomic_store(hu + 1, h1.u, __ATOMIC_RELAXED, __HIP_MEMORY_SCOPE_AGENT);
      }

      __syncthreads();   // barC: per-wave vmcnt drained -> stores ACKed at LLC
      if (threadIdx.x == 0)
        __hip_atomic_store(flg + bb, (unsigned)(s + 1), __ATOMIC_RELAXED,
                           __HIP_MEMORY_SCOPE_AGENT);
    }
  } else {
    // ================= xw-GEMM role: 4 x (64x64) tiles per block ==========
    // gid interleaves directions so both dirs' chunk-0 tiles dispatch first;
    // fwd computes t-chunks ascending, bwd descending (matches consumption).
    const int gid  = b - NREC;          // 0..1023
    const int dir  = gid & 1;
    const int rr   = gid >> 1;          // 0..511
    int bm = rr >> 3;                   // 0..63
    if (dir) bm = 63 - bm;
    const int quad = rr & 7;            // 0..7
    const int grp  = threadIdx.x >> 8;  // 0..3 (one 64x64 tile each)
    const int tid  = threadIdx.x & 255;
    const float* __restrict__ B    = dir ? Wxb : Wxf;
    const float* __restrict__ bias = dir ? bhb : bhf;
    float* __restrict__ C          = dir ? xwb : xwf;
    unsigned* __restrict__ cnt     = prog + (dir ? 192 : 128);
    const int bm0 = bm * 64;                   // T rows
    const int bn0 = (quad * 4 + grp) * 64;     // H cols

    const int ty = tid >> 4, tx = tid & 15;
    const int lrow = tid >> 2, lkq = (tid & 3) << 2;
    float acc[4][4] = {};

    for (int k0 = 0; k0 < IN_N; k0 += 16) {
      float4 a4 = *(const float4*)(x + (size_t)(bm0 + lrow) * IN_N + k0 + lkq);
      float4 b4 = *(const float4*)(B + (size_t)(bn0 + lrow) * IN_N + k0 + lkq);
      As[grp][lkq + 0][lrow] = a4.x; As[grp][lkq + 1][lrow] = a4.y;
      As[grp][lkq + 2][lrow] = a4.z; As[grp][lkq + 3][lrow] = a4.w;
      Bs[grp][lkq + 0][lrow] = b4.x; Bs[grp][lkq + 1][lrow] = b4.y;
      Bs[grp][lkq + 2][lrow] = b4.z; Bs[grp][lkq + 3][lrow] = b4.w;
      __syncthreads();   // block-wide; all 4 groups share the same schedule
#pragma unroll
      for (int k = 0; k < 16; ++k) {
        float a[4], bv[4];
#pragma unroll
        for (int i = 0; i < 4; ++i) a[i] = As[grp][k][ty * 4 + i];
#pragma unroll
        for (int j = 0; j < 4; ++j) bv[j] = Bs[grp][k][tx * 4 + j];
#pragma unroll
        for (int i = 0; i < 4; ++i)
#pragma unroll
          for (int j = 0; j < 4; ++j) acc[i][j] = fmaf(a[i], bv[j], acc[i][j]);
      }
      __syncthreads();
    }
    // C-write via 8B sc1 atomic stores (LLC-direct; consumers read sc1).
#pragma unroll
    for (int i = 0; i < 4; ++i) {
      union { float f; unsigned u; } v[4];
      v[0].f = acc[i][0] + bias[bn0 + tx * 4 + 0];
      v[1].f = acc[i][1] + bias[bn0 + tx * 4 + 1];
      v[2].f = acc[i][2] + bias[bn0 + tx * 4 + 2];
      v[3].f = acc[i][3] + bias[bn0 + tx * 4 + 3];
      unsigned long long p0 = ((unsigned long long)v[1].u << 32) | v[0].u;
      unsigned long long p1 = ((unsigned long long)v[3].u << 32) | v[2].u;
      unsigned long long* dst = (unsigned long long*)
          (C + (size_t)(bm0 + ty * 4 + i) * H_N + bn0 + tx * 4);
      __hip_atomic_store(dst + 0, p0, __ATOMIC_RELAXED, __HIP_MEMORY_SCOPE_AGENT);
      __hip_atomic_store(dst + 1, p1, __ATOMIC_RELAXED, __HIP_MEMORY_SCOPE_AGENT);
    }
    __syncthreads();   // all waves' sc1 stores ACKed at LLC
    if (threadIdx.x == 0)
      __hip_atomic_fetch_add(cnt + bm, 4u, __ATOMIC_RELAXED,
                             __HIP_MEMORY_SCOPE_AGENT);
  }
}

// ---------------------------------------------------------------------------
// Output GEMM (unchanged): y = hf@Wyf^T + hb@Wyb^T + by
// ---------------------------------------------------------------------------
__global__ __launch_bounds__(256) void gemm_out_kernel(
    const float* __restrict__ hf, const float* __restrict__ hb,
    const float* __restrict__ Wyf, const float* __restrict__ Wyb,
    const float* __restrict__ by, float* __restrict__ y)
{
  const int bm0 = blockIdx.y * 64;   // T dim
  const int bn0 = blockIdx.x * 64;   // OUT dim
  __shared__ float As[16][65];
  __shared__ float Bs[16][65];
  const int tid  = threadIdx.x;
  const int ty   = tid >> 4, tx = tid & 15;
  const int lrow = tid >> 2, lkq = (tid & 3) << 2;
  float acc[4][4] = {};

#pragma unroll 1
  for (int pass = 0; pass < 2; ++pass) {
    const float* __restrict__ A = pass ? hb : hf;
    const float* __restrict__ B = pass ? Wyb : Wyf;
    for (int k0 = 0; k0 < H_N; k0 += 16) {
      float4 a4 = *(const float4*)(A + (size_t)(bm0 + lrow) * H_N + k0 + lkq);
      float4 b4 = *(const float4*)(B + (size_t)(bn0 + lrow) * H_N + k0 + lkq);
      As[lkq + 0][lrow] = a4.x; As[lkq + 1][lrow] = a4.y;
      As[lkq + 2][lrow] = a4.z; As[lkq + 3][lrow] = a4.w;
      Bs[lkq + 0][lrow] = b4.x; Bs[lkq + 1][lrow] = b4.y;
      Bs[lkq + 2][lrow] = b4.z; Bs[lkq + 3][lrow] = b4.w;
      __syncthreads();
#pragma unroll
      for (int k = 0; k < 16; ++k) {
        float a[4], bv[4];
#pragma unroll
        for (int i = 0; i < 4; ++i) a[i] = As[k][ty * 4 + i];
#pragma unroll
        for (int j = 0; j < 4; ++j) bv[j] = Bs[k][tx * 4 + j];
#pragma unroll
        for (int i = 0; i < 4; ++i)
#pragma unroll
          for (int j = 0; j < 4; ++j) acc[i][j] = fmaf(a[i], bv[j], acc[i][j]);
      }
      __syncthreads();
    }
  }
#pragma unroll
  for (int i = 0; i < 4; ++i) {
    float4 v;
    v.x = acc[i][0] + by[bn0 + tx * 4 + 0];
    v.y = acc[i][1] + by[bn0 + tx * 4 + 1];
    v.z = acc[i][2] + by[bn0 + tx * 4 + 2];
    v.w = acc[i][3] + by[bn0 + tx * 4 + 3];
    *(float4*)(y + (size_t)(bm0 + ty * 4 + i) * OUT_N + bn0 + tx * 4) = v;
  }
}

extern "C" void kernel_launch(void* const* d_in, const int* in_sizes, int n_in,
                              void* d_out, int out_size, void* d_ws, size_t ws_size,
                              hipStream_t stream) {
  const float* x   = (const float*)d_in[0];
  const float* Wxf = (const float*)d_in[1];
  const float* Whf = (const float*)d_in[2];
  const float* bhf = (const float*)d_in[3];
  const float* Wxb = (const float*)d_in[4];
  const float* Whb = (const float*)d_in[5];
  const float* bhb = (const float*)d_in[6];
  const float* Wyf = (const float*)d_in[7];
  const float* Wyb = (const float*)d_in[8];
  const float* by  = (const float*)d_in[9];
  float* y = (float*)d_out;

  char* ws = (char*)d_ws;
  float* xwf     = (float*)(ws + XW_F_OFF);
  float* xwb     = (float*)(ws + XW_B_OFF);
  float* hf      = (float*)(ws + HF_OFF);
  float* hb      = (float*)(ws + HB_OFF);
  unsigned* prog = (unsigned*)(ws + PROG_OFF);

  hipLaunchKernelGGL(init_prog_kernel, dim3(1), dim3(256), 0, stream, prog);
  hipLaunchKernelGGL(mega_kernel, dim3(NREC + NGEMM), dim3(RTH), 0, stream,
                     x, Wxf, bhf, Wxb, bhb, Whf, Whb, xwf, xwb, hf, hb, prog);
  hipLaunchKernelGGL(gemm_out_kernel, dim3(OUT_N / 64, T_N / 64), dim3(256), 0, stream,
                     hf, hb, Wyf, Wyb, by, y);
}